// Round 2
// baseline (703.417 us; speedup 1.0000x reference)
//
#include <hip/hip_runtime.h>
#include <stdint.h>

#define KCB 196560   // codebook rows
#define DIM 24       // embed dim
#define BB  2        // batch
#define ZEL 12288    // B*D*16*16
#define NRB 384      // row-blocks for MFMA score (384*512 = 196608 >= 196560)
#define RBS 512      // rows per score block

typedef __attribute__((ext_vector_type(8)))  __bf16 bf16x8;
typedef __attribute__((ext_vector_type(16))) float  f32x16;

__device__ __forceinline__ unsigned long long pack_key(float sim, int idx) {
  unsigned u = __float_as_uint(sim);
  u = (u & 0x80000000u) ? ~u : (u | 0x80000000u);       // order-preserving float->u32
  return ((unsigned long long)u << 32) | (unsigned)(~(unsigned)idx); // smaller idx wins ties
}

// ---------- init: residual = z, zero the whole output (verbatim) ----------
__global__ __launch_bounds__(256) void init_kernel(const float* __restrict__ z,
    float* __restrict__ residual, float* __restrict__ out, int outTotal) {
  int e = blockIdx.x * 256 + threadIdx.x;
  if (e < ZEL) residual[e] = z[e];
  if (e < outTotal) out[e] = 0.0f;
}

// ---------- codebook prep (once per call): f32 -> truncated-bf16 hi, row-major ----------
// thread = (row, quad q): reads float4 cb[row*24 + 4q], writes 4 bf16-hi as uint2.
__global__ __launch_bounds__(256) void cbprep_kernel(const float* __restrict__ cb,
    ushort* __restrict__ ch) {
  int j = blockIdx.x * 256 + threadIdx.x;
  if (j >= KCB * 6) return;
  int row = j / 6, q = j - row * 6;
  float4 v = *(const float4*)(cb + (size_t)row * 24 + q * 4);
  unsigned b0 = __float_as_uint(v.x) >> 16;
  unsigned b1 = __float_as_uint(v.y) >> 16;
  unsigned b2 = __float_as_uint(v.z) >> 16;
  unsigned b3 = __float_as_uint(v.w) >> 16;
  *(uint2*)(ch + (size_t)row * 24 + q * 4) = make_uint2(b0 | (b1 << 16), b2 | (b3 << 16));
}

// ---------- fused downsample + token pack ----------
// thread = (token, quad q): computes rdown for d=4q..4q+3 with the EXACT same
// weight + fmaf chain as the proven down_kernel (rdown bits identical), then
// packs token hi/lo truncated-bf16 fragments.
__global__ __launch_bounds__(256) void down_pack_kernel(const float* __restrict__ residual,
    float* __restrict__ rdown, ushort* __restrict__ th, ushort* __restrict__ tl,
    int t, int n) {
  int j = blockIdx.x * 256 + threadIdx.x;
  int T = BB * n;
  if (j >= 6 * T) return;
  int token = j / 6, q = j - token * 6;
  int b = token / n, sp = token - b * n;
  int oh = sp / t, ow = sp - oh * t;
  float inv_scale = 16.0f / (float)t;
  float ks = inv_scale;
  float sf_h = ((float)oh + 0.5f) * inv_scale - 0.5f;
  float sf_w = ((float)ow + 0.5f) * inv_scale - 0.5f;
  float wh[16], ww[16];
  float sh = 0.f, sw = 0.f;
#pragma unroll
  for (int i = 0; i < 16; ++i) {
    float vh = fmaxf(0.f, 1.f - fabsf(sf_h - (float)i) / ks);
    wh[i] = vh; sh += vh;
    float vw = fmaxf(0.f, 1.f - fabsf(sf_w - (float)i) / ks);
    ww[i] = vw; sw += vw;
  }
#pragma unroll
  for (int i = 0; i < 16; ++i) { wh[i] /= sh; ww[i] /= sw; }
  float acc4[4];
#pragma unroll
  for (int dd = 0; dd < 4; ++dd) {
    int d = q * 4 + dd;
    const float* resb = residual + (b * DIM + d) * 256;
    float acc = 0.f;
    for (int ih = 0; ih < 16; ++ih) {
      float ra = 0.f;
#pragma unroll
      for (int iw = 0; iw < 16; ++iw) ra = fmaf(ww[iw], resb[ih * 16 + iw], ra);
      acc = fmaf(wh[ih], ra, acc);
    }
    acc4[dd] = acc;
  }
  *(float4*)(rdown + (size_t)token * 24 + q * 4) =
      make_float4(acc4[0], acc4[1], acc4[2], acc4[3]);
  unsigned h[4], l[4];
#pragma unroll
  for (int dd = 0; dd < 4; ++dd) {
    unsigned bits = __float_as_uint(acc4[dd]);
    h[dd] = bits >> 16;
    float hif = __uint_as_float(bits & 0xffff0000u);
    l[dd] = __float_as_uint(acc4[dd] - hif) >> 16;   // exact in fp32
  }
  *(uint2*)(th + (size_t)token * 24 + q * 4) = make_uint2(h[0] | (h[1] << 16), h[2] | (h[3] << 16));
  *(uint2*)(tl + (size_t)token * 24 + q * 4) = make_uint2(l[0] | (l[1] << 16), l[2] | (l[3] << 16));
}

// ---------- MFMA score: per-token, per-512-row-block approx max similarity ----------
// sim ~ c_hi . (t_hi + t_lo); K padded 24->32. All fragments pre-packed -> pure loads.
// A frag (codebook hi): row = lane&31, k = 8*(lane>>5)+j.  B frag (tokens): col = lane&31.
// D: col = lane&31 (token), row = (reg&3)+8*(reg>>2)+4*(lane>>5) (codebook row).
__global__ __launch_bounds__(256) void score_kernel(const ushort* __restrict__ ch,
    const ushort* __restrict__ th, const ushort* __restrict__ tl,
    float* __restrict__ blockmax, int T) {
  const int bx = blockIdx.x;
  const int rb = bx % NRB, tb = bx / NRB;
  const int tid = threadIdx.x, lane = tid & 63, wv = tid >> 6;
  const int col = lane & 31, g = lane >> 5;
  const int tbase = tb * 128;
  const int ntt = min(4, (T - tbase + 31) >> 5);
  const uint4 z4 = make_uint4(0, 0, 0, 0);

  // --- token (B) fragments, persistent in registers (pure loads) ---
  bf16x8 bh[4][2], bl[4][2];
#pragma unroll
  for (int tt = 0; tt < 4; ++tt) {
    int token = tbase + tt * 32 + col;
    bool tv = (tt < ntt) && (token < T);
    const ushort* tr = th + (size_t)token * 24;
    const ushort* sr = tl + (size_t)token * 24;
    uint4 h0 = tv ? *(const uint4*)(tr + g * 8) : z4;
    uint4 h1 = (tv && g == 0) ? *(const uint4*)(tr + 16) : z4;   // k16..23 (g1 -> pad 0)
    uint4 l0 = tv ? *(const uint4*)(sr + g * 8) : z4;
    uint4 l1 = (tv && g == 0) ? *(const uint4*)(sr + 16) : z4;
    bh[tt][0] = __builtin_bit_cast(bf16x8, h0);
    bh[tt][1] = __builtin_bit_cast(bf16x8, h1);
    bl[tt][0] = __builtin_bit_cast(bf16x8, l0);
    bl[tt][1] = __builtin_bit_cast(bf16x8, l1);
  }

  const f32x16 fzero = {};
  float runmax[4] = {-3.402823466e38f, -3.402823466e38f, -3.402823466e38f, -3.402823466e38f};
  const int rbase = rb * RBS + wv * 128;

#pragma unroll
  for (int rt = 0; rt < 4; ++rt) {
    int tilebase = rbase + rt * 32;
    if (tilebase >= KCB) continue;               // wave-uniform
    int row = tilebase + col;
    bool rv = row < KCB;
    const ushort* cr = ch + (size_t)row * 24;
    uint4 a0 = rv ? *(const uint4*)(cr + g * 8) : z4;
    uint4 a1 = (rv && g == 0) ? *(const uint4*)(cr + 16) : z4;
    bf16x8 ah0 = __builtin_bit_cast(bf16x8, a0);
    bf16x8 ah1 = __builtin_bit_cast(bf16x8, a1);
    int limit = KCB - tilebase;                  // >= 32 except the single partial tile
    bool full = limit >= 32;
#pragma unroll
    for (int tt = 0; tt < 4; ++tt) {
      if (tt >= ntt) continue;
      f32x16 acc = __builtin_amdgcn_mfma_f32_32x32x16_bf16(ah0, bh[tt][0], fzero, 0, 0, 0);
      acc = __builtin_amdgcn_mfma_f32_32x32x16_bf16(ah1, bh[tt][1], acc, 0, 0, 0);
      acc = __builtin_amdgcn_mfma_f32_32x32x16_bf16(ah0, bl[tt][0], acc, 0, 0, 0);
      acc = __builtin_amdgcn_mfma_f32_32x32x16_bf16(ah1, bl[tt][1], acc, 0, 0, 0);
      float m;
      if (full) {
        float m01 = fmaxf(acc[0], acc[1]),  m23 = fmaxf(acc[2], acc[3]);
        float m45 = fmaxf(acc[4], acc[5]),  m67 = fmaxf(acc[6], acc[7]);
        float m89 = fmaxf(acc[8], acc[9]),  mab = fmaxf(acc[10], acc[11]);
        float mcd = fmaxf(acc[12], acc[13]), mef = fmaxf(acc[14], acc[15]);
        m = fmaxf(fmaxf(fmaxf(m01, m23), fmaxf(m45, m67)),
                  fmaxf(fmaxf(m89, mab), fmaxf(mcd, mef)));
      } else {
        m = -3.402823466e38f;                    // mask rows >= KCB so sims can't be fake 0
#pragma unroll
        for (int r = 0; r < 16; ++r) {
          int rowid = (r & 3) + 8 * (r >> 2) + 4 * g;
          if (rowid < limit) m = fmaxf(m, acc[r]);
        }
      }
      runmax[tt] = fmaxf(runmax[tt], m);
    }
  }

  __shared__ float lmax[4][4][32];
#pragma unroll
  for (int tt = 0; tt < 4; ++tt) {
    float v = fmaxf(runmax[tt], __shfl_xor(runmax[tt], 32));
    if (lane < 32) lmax[wv][tt][col] = v;
  }
  __syncthreads();
  if (tid < 128) {
    int tt = tid >> 5, c = tid & 31;
    if (tt < ntt) {
      float m = fmaxf(fmaxf(lmax[0][tt][c], lmax[1][tt][c]),
                      fmaxf(lmax[2][tt][c], lmax[3][tt][c]));
      int token = tbase + tt * 32 + c;
      if (token < T) blockmax[token * NRB + rb] = m;
    }
  }
}

// ---------- exact finalize: prune by blockmax, rescan candidates with the EXACT
// ascending-k fmaf chain + strict-> / lowest-index tie-break (bit-identical output) ----
__global__ __launch_bounds__(256) void finalize_kernel(const float* __restrict__ cb,
    const float* __restrict__ rdown, const float* __restrict__ blockmax,
    unsigned long long* __restrict__ best, int T) {
  int tid = threadIdx.x, lane = tid & 63, wv = tid >> 6;
  int tok = blockIdx.x * 4 + wv;                 // one wave per token
  if (tok >= T) return;

  float x = (lane < DIM) ? rdown[tok * DIM + lane] : 0.f;
  float av[DIM];
#pragma unroll
  for (int k = 0; k < DIM; ++k)
    av[k] = __uint_as_float(__builtin_amdgcn_readlane(__float_as_uint(x), k));
  float ss = 0.f;
#pragma unroll
  for (int k = 0; k < DIM; ++k) ss = fmaf(av[k], av[k], ss);
  // sim error bound for c_hi.(t_hi+t_lo): (2^-7 + 2^-14)|t| ~ 0.0079|t|.
  // eps = 0.02|t| > 2x bound (covers M over-estimate AND candidate under-estimate).
  float eps = 0.02f * sqrtf(ss) + 1e-30f;

  const float* bmrow = blockmax + (size_t)tok * NRB;
  float bv[6];
#pragma unroll
  for (int i = 0; i < 6; ++i) bv[i] = bmrow[lane + 64 * i];   // 384 = 64*6
  float M = fmaxf(fmaxf(fmaxf(bv[0], bv[1]), fmaxf(bv[2], bv[3])), fmaxf(bv[4], bv[5]));
#pragma unroll
  for (int d = 32; d; d >>= 1) M = fmaxf(M, __shfl_xor(M, d));
  float thr = M - eps;

  unsigned long long bk = 0ull;
#pragma unroll
  for (int i = 0; i < 6; ++i) {
    unsigned long long mask = __ballot(bv[i] >= thr);
    while (mask) {                                // wave-uniform loop, expected ~2 iters total
      int l = __ffsll((unsigned long long)mask) - 1;
      mask &= mask - 1;
      int rowb = (l + 64 * i) * RBS;
      for (int r8 = 0; r8 < 8; ++r8) {
        int row = rowb + r8 * 64 + lane;
        if (row < KCB) {
          const float* cv = cb + (size_t)row * DIM;
          float acc = 0.f;
#pragma unroll
          for (int k = 0; k < DIM; ++k) acc = fmaf(av[k], cv[k], acc);  // exact chain
          unsigned long long key = pack_key(acc, row);
          if (key > bk) bk = key;                 // rows ascend per lane -> lowest idx kept
        }
      }
    }
  }
#pragma unroll
  for (int d = 32; d; d >>= 1) {
    unsigned long long o = __shfl_xor(bk, d);
    if (o > bk) bk = o;
  }
  if (lane == 0) best[tok] = bk;
}

// ---------- update (verbatim): gather zq, upsample, z_hat/residual, indices ----------
template<int TSZ>
__global__ __launch_bounds__(256) void update_kernel(const float* __restrict__ cb,
    const unsigned long long* __restrict__ best, float* __restrict__ residual,
    float* __restrict__ out, int idxBase) {
  constexpr int N = TSZ * TSZ;
  constexpr int T = BB * N;
  __shared__ float zq[T * DIM];
  int tid = threadIdx.x;
  for (int slot = tid; slot < T; slot += 256) {
    unsigned long long key = best[slot];
    int idx = (int)(~(unsigned)key);
    const float* cv = cb + (long long)idx * DIM;
    float v[DIM]; float ss = 0.f;
#pragma unroll
    for (int k = 0; k < DIM; ++k) { v[k] = cv[k]; ss = fmaf(v[k], v[k], ss); }
    float nrm = sqrtf(ss);
#pragma unroll
    for (int k = 0; k < DIM; ++k) zq[slot * DIM + k] = v[k] / nrm;
    if (blockIdx.x == 0) out[idxBase + slot] = (float)idx;
  }
  __syncthreads();
  int e = blockIdx.x * 256 + tid;
  int w = e & 15, h = (e >> 4) & 15;
  int d = (e >> 8) % DIM;
  int b = e / (DIM * 256);
  float inv_scale = (float)TSZ / 16.0f;
  float sf_h = ((float)h + 0.5f) * inv_scale - 0.5f;
  float sf_w = ((float)w + 0.5f) * inv_scale - 0.5f;
  float wh[TSZ], ww[TSZ];
  float sh = 0.f, sw = 0.f;
#pragma unroll
  for (int j = 0; j < TSZ; ++j) {
    float vh = fmaxf(0.f, 1.f - fabsf(sf_h - (float)j));
    wh[j] = vh; sh += vh;
    float vw = fmaxf(0.f, 1.f - fabsf(sf_w - (float)j));
    ww[j] = vw; sw += vw;
  }
#pragma unroll
  for (int j = 0; j < TSZ; ++j) { wh[j] /= sh; ww[j] /= sw; }
  const float* zb = zq + (b * N) * DIM + d;
  float acc = 0.f;
#pragma unroll
  for (int th = 0; th < TSZ; ++th) {
    float ra = 0.f;
#pragma unroll
    for (int tw = 0; tw < TSZ; ++tw) ra = fmaf(ww[tw], zb[(th * TSZ + tw) * DIM], ra);
    acc = fmaf(wh[th], ra, acc);
  }
  out[e] += acc;
  residual[e] -= acc;
}

// ---------- host ----------
extern "C" void kernel_launch(void* const* d_in, const int* in_sizes, int n_in,
                              void* d_out, int out_size, void* d_ws, size_t ws_size,
                              hipStream_t stream) {
  const float* z  = (const float*)d_in[0];
  const float* cb = (const float*)d_in[1];
  float* out = (float*)d_out;
  float* residual = (float*)d_ws;                          // 12288 f
  float* rdown = residual + ZEL;                           // 12288 f
  float* blockmax = rdown + ZEL;                           // 512*384 f
  unsigned long long* best =
      (unsigned long long*)(blockmax + 512 * NRB);         // 512 u64
  ushort* th = (ushort*)(best + 512);                      // 512*24 u16 token hi
  ushort* tl = th + 512 * 24;                              // 512*24 u16 token lo
  ushort* ch = tl + 512 * 24;                              // 196560*24 u16 codebook hi

  static const int TS[10] = {1, 2, 3, 4, 5, 6, 8, 10, 13, 16};

  init_kernel<<<(out_size + 255) / 256, 256, 0, stream>>>(z, residual, out, out_size);
  cbprep_kernel<<<(KCB * 6 + 255) / 256, 256, 0, stream>>>(cb, ch);

  int prefix = 0;
  for (int s = 0; s < 10; ++s) {
    int t = TS[s], n = t * t, T = BB * n;
    down_pack_kernel<<<(6 * T + 255) / 256, 256, 0, stream>>>(residual, rdown, th, tl, t, n);

    int ntb = (T + 127) >> 7;
    score_kernel<<<NRB * ntb, 256, 0, stream>>>(ch, th, tl, blockmax, T);
    finalize_kernel<<<(T + 3) / 4, 256, 0, stream>>>(cb, rdown, blockmax, best, T);

    int idxBase = ZEL + BB * prefix;
    switch (t) {
      case 1:  update_kernel<1><<<48, 256, 0, stream>>>(cb, best, residual, out, idxBase); break;
      case 2:  update_kernel<2><<<48, 256, 0, stream>>>(cb, best, residual, out, idxBase); break;
      case 3:  update_kernel<3><<<48, 256, 0, stream>>>(cb, best, residual, out, idxBase); break;
      case 4:  update_kernel<4><<<48, 256, 0, stream>>>(cb, best, residual, out, idxBase); break;
      case 5:  update_kernel<5><<<48, 256, 0, stream>>>(cb, best, residual, out, idxBase); break;
      case 6:  update_kernel<6><<<48, 256, 0, stream>>>(cb, best, residual, out, idxBase); break;
      case 8:  update_kernel<8><<<48, 256, 0, stream>>>(cb, best, residual, out, idxBase); break;
      case 10: update_kernel<10><<<48, 256, 0, stream>>>(cb, best, residual, out, idxBase); break;
      case 13: update_kernel<13><<<48, 256, 0, stream>>>(cb, best, residual, out, idxBase); break;
      case 16: update_kernel<16><<<48, 256, 0, stream>>>(cb, best, residual, out, idxBase); break;
    }
    prefix += n;
  }
}

// Round 3
// 350.902 us; speedup vs baseline: 2.0046x; 2.0046x over previous
//
#include <hip/hip_runtime.h>
#include <stdint.h>

#define KCB 196560   // codebook rows
#define DIM 24       // embed dim
#define BB  2        // batch
#define ZEL 12288    // B*D*16*16
#define NRB 384      // row-blocks for MFMA score (384*512 = 196608 >= 196560)
#define RBS 512      // rows per score block

typedef __attribute__((ext_vector_type(8)))  __bf16 bf16x8;
typedef __attribute__((ext_vector_type(16))) float  f32x16;

__device__ __forceinline__ unsigned long long pack_key(float sim, int idx) {
  unsigned u = __float_as_uint(sim);
  u = (u & 0x80000000u) ? ~u : (u | 0x80000000u);       // order-preserving float->u32
  return ((unsigned long long)u << 32) | (unsigned)(~(unsigned)idx); // smaller idx wins ties
}

// ---------- fused init: residual = z, zero out, t=1 downsample+pack ----------
__global__ __launch_bounds__(256) void init_kernel(const float* __restrict__ z,
    float* __restrict__ residual, float* __restrict__ out, float* __restrict__ rdown,
    ushort* __restrict__ th, ushort* __restrict__ tl, int outTotal) {
  __shared__ float plane[256];
  int tid = threadIdx.x;
  int e = blockIdx.x * 256 + tid;
  if (e < outTotal) out[e] = 0.0f;
  if (blockIdx.x < 48) {                       // 48 blocks = 48 (b,d) planes
    float v = z[e];
    residual[e] = v;
    plane[tid] = v;
    __syncthreads();
    if (tid == 0) {                            // t=1: single token per plane
      int t = 1;
      float inv_scale = 16.0f / (float)t;
      float ks = inv_scale;
      float sf_h = (0.0f + 0.5f) * inv_scale - 0.5f;
      float sf_w = (0.0f + 0.5f) * inv_scale - 0.5f;
      float wh[16], ww[16];
      float sh = 0.f, sw = 0.f;
#pragma unroll
      for (int i = 0; i < 16; ++i) {
        float vh = fmaxf(0.f, 1.f - fabsf(sf_h - (float)i) / ks);
        wh[i] = vh; sh += vh;
        float vw = fmaxf(0.f, 1.f - fabsf(sf_w - (float)i) / ks);
        ww[i] = vw; sw += vw;
      }
#pragma unroll
      for (int i = 0; i < 16; ++i) { wh[i] /= sh; ww[i] /= sw; }
      float acc = 0.f;
      for (int ih = 0; ih < 16; ++ih) {
        float ra = 0.f;
#pragma unroll
        for (int iw = 0; iw < 16; ++iw) ra = fmaf(ww[iw], plane[ih * 16 + iw], ra);
        acc = fmaf(wh[ih], ra, acc);
      }
      int b = blockIdx.x / DIM, d = blockIdx.x - (blockIdx.x / DIM) * DIM;
      int token = b;                           // n=1, sp=0
      rdown[token * DIM + d] = acc;
      unsigned bits = __float_as_uint(acc);
      float hif = __uint_as_float(bits & 0xffff0000u);
      th[token * DIM + d] = (ushort)(bits >> 16);
      tl[token * DIM + d] = (ushort)(__float_as_uint(acc - hif) >> 16);
    }
  }
}

// ---------- codebook prep (once per call): f32 -> truncated-bf16 hi + lo planes ----------
__global__ __launch_bounds__(256) void cbprep_kernel(const float* __restrict__ cb,
    ushort* __restrict__ ch, ushort* __restrict__ cl) {
  int j = blockIdx.x * 256 + threadIdx.x;
  if (j >= KCB * 6) return;
  int row = j / 6, q = j - row * 6;
  float4 v = *(const float4*)(cb + (size_t)row * 24 + q * 4);
  float xs[4] = {v.x, v.y, v.z, v.w};
  unsigned h[4], l[4];
#pragma unroll
  for (int k = 0; k < 4; ++k) {
    unsigned bits = __float_as_uint(xs[k]);
    h[k] = bits >> 16;
    float hif = __uint_as_float(bits & 0xffff0000u);
    l[k] = __float_as_uint(xs[k] - hif) >> 16;   // exact in fp32
  }
  *(uint2*)(ch + (size_t)row * 24 + q * 4) = make_uint2(h[0] | (h[1] << 16), h[2] | (h[3] << 16));
  *(uint2*)(cl + (size_t)row * 24 + q * 4) = make_uint2(l[0] | (l[1] << 16), l[2] | (l[3] << 16));
}

// ---------- MFMA score: per-token, per-512-row-block approx max similarity ----------
// sim ~ (c_hi + c_lo).t_hi + c_hi.t_lo  (round-1 proven terms, eps=1e-3 semantics).
// Fragments pre-packed -> pure loads. A frag: row = lane&31, k = 8*(lane>>5)+j.
// D: col = lane&31 (token), row = (reg&3)+8*(reg>>2)+4*(lane>>5).
__global__ __launch_bounds__(256) void score_kernel(const ushort* __restrict__ ch,
    const ushort* __restrict__ cl, const ushort* __restrict__ th,
    const ushort* __restrict__ tl, float* __restrict__ blockmax, int T) {
  const int bx = blockIdx.x;
  const int rb = bx % NRB, tb = bx / NRB;
  const int tid = threadIdx.x, lane = tid & 63, wv = tid >> 6;
  const int col = lane & 31, g = lane >> 5;
  const int tbase = tb * 128;
  const int ntt = min(4, (T - tbase + 31) >> 5);
  const uint4 z4 = make_uint4(0, 0, 0, 0);

  // token (B) fragments, persistent in registers (pure loads)
  bf16x8 bh[4][2], bl[4][2];
#pragma unroll
  for (int tt = 0; tt < 4; ++tt) {
    int token = tbase + tt * 32 + col;
    bool tv = (tt < ntt) && (token < T);
    const ushort* tr = th + (size_t)token * 24;
    const ushort* sr = tl + (size_t)token * 24;
    uint4 h0 = tv ? *(const uint4*)(tr + g * 8) : z4;
    uint4 h1 = (tv && g == 0) ? *(const uint4*)(tr + 16) : z4;   // k16..23 (g1 -> pad 0)
    uint4 l0 = tv ? *(const uint4*)(sr + g * 8) : z4;
    uint4 l1 = (tv && g == 0) ? *(const uint4*)(sr + 16) : z4;
    bh[tt][0] = __builtin_bit_cast(bf16x8, h0);
    bh[tt][1] = __builtin_bit_cast(bf16x8, h1);
    bl[tt][0] = __builtin_bit_cast(bf16x8, l0);
    bl[tt][1] = __builtin_bit_cast(bf16x8, l1);
  }

  const f32x16 fzero = {};
  float runmax[4] = {-3.402823466e38f, -3.402823466e38f, -3.402823466e38f, -3.402823466e38f};
  const int rbase = rb * RBS + wv * 128;

#pragma unroll
  for (int rt = 0; rt < 4; ++rt) {
    int tilebase = rbase + rt * 32;
    if (tilebase >= KCB) continue;               // wave-uniform
    int row = tilebase + col;
    bool rv = row < KCB;
    const ushort* cr = ch + (size_t)row * 24;
    const ushort* dr = cl + (size_t)row * 24;
    uint4 a0 = rv ? *(const uint4*)(cr + g * 8) : z4;
    uint4 a1 = (rv && g == 0) ? *(const uint4*)(cr + 16) : z4;
    uint4 c0 = rv ? *(const uint4*)(dr + g * 8) : z4;
    uint4 c1 = (rv && g == 0) ? *(const uint4*)(dr + 16) : z4;
    bf16x8 ah0 = __builtin_bit_cast(bf16x8, a0);
    bf16x8 ah1 = __builtin_bit_cast(bf16x8, a1);
    bf16x8 al0 = __builtin_bit_cast(bf16x8, c0);
    bf16x8 al1 = __builtin_bit_cast(bf16x8, c1);
    int limit = KCB - tilebase;                  // >= 32 except the single partial tile
    bool full = limit >= 32;
#pragma unroll
    for (int tt = 0; tt < 4; ++tt) {
      if (tt >= ntt) continue;
      f32x16 acc = __builtin_amdgcn_mfma_f32_32x32x16_bf16(ah0, bh[tt][0], fzero, 0, 0, 0);
      acc = __builtin_amdgcn_mfma_f32_32x32x16_bf16(ah1, bh[tt][1], acc, 0, 0, 0);
      acc = __builtin_amdgcn_mfma_f32_32x32x16_bf16(al0, bh[tt][0], acc, 0, 0, 0);
      acc = __builtin_amdgcn_mfma_f32_32x32x16_bf16(al1, bh[tt][1], acc, 0, 0, 0);
      acc = __builtin_amdgcn_mfma_f32_32x32x16_bf16(ah0, bl[tt][0], acc, 0, 0, 0);
      acc = __builtin_amdgcn_mfma_f32_32x32x16_bf16(ah1, bl[tt][1], acc, 0, 0, 0);
      float m;
      if (full) {
        float m01 = fmaxf(acc[0], acc[1]),  m23 = fmaxf(acc[2], acc[3]);
        float m45 = fmaxf(acc[4], acc[5]),  m67 = fmaxf(acc[6], acc[7]);
        float m89 = fmaxf(acc[8], acc[9]),  mab = fmaxf(acc[10], acc[11]);
        float mcd = fmaxf(acc[12], acc[13]), mef = fmaxf(acc[14], acc[15]);
        m = fmaxf(fmaxf(fmaxf(m01, m23), fmaxf(m45, m67)),
                  fmaxf(fmaxf(m89, mab), fmaxf(mcd, mef)));
      } else {
        m = -3.402823466e38f;                    // mask rows >= KCB so sims can't be fake 0
#pragma unroll
        for (int r = 0; r < 16; ++r) {
          int rowid = (r & 3) + 8 * (r >> 2) + 4 * g;
          if (rowid < limit) m = fmaxf(m, acc[r]);
        }
      }
      runmax[tt] = fmaxf(runmax[tt], m);
    }
  }

  __shared__ float lmax[4][4][32];
#pragma unroll
  for (int tt = 0; tt < 4; ++tt) {
    float v = fmaxf(runmax[tt], __shfl_xor(runmax[tt], 32));
    if (lane < 32) lmax[wv][tt][col] = v;
  }
  __syncthreads();
  if (tid < 128) {
    int tt = tid >> 5, c = tid & 31;
    if (tt < ntt) {
      float m = fmaxf(fmaxf(lmax[0][tt][c], lmax[1][tt][c]),
                      fmaxf(lmax[2][tt][c], lmax[3][tt][c]));
      int token = tbase + tt * 32 + c;
      if (token < T) blockmax[token * NRB + rb] = m;
    }
  }
}

// ---------- exact finalize (round-1 verbatim, eps=1e-3): prune + exact rescan ----------
__global__ __launch_bounds__(256) void finalize_kernel(const float* __restrict__ cb,
    const float* __restrict__ rdown, const float* __restrict__ blockmax,
    unsigned long long* __restrict__ best, int T) {
  int tid = threadIdx.x, lane = tid & 63, wv = tid >> 6;
  int tok = blockIdx.x * 4 + wv;                 // one wave per token
  if (tok >= T) return;

  float x = (lane < DIM) ? rdown[tok * DIM + lane] : 0.f;
  float av[DIM];
#pragma unroll
  for (int k = 0; k < DIM; ++k)
    av[k] = __uint_as_float(__builtin_amdgcn_readlane(__float_as_uint(x), k));
  float ss = 0.f;
#pragma unroll
  for (int k = 0; k < DIM; ++k) ss = fmaf(av[k], av[k], ss);
  // eps = 1e-3*|a| >= 5x the split-bf16 error bound (~3*2^-14*|a|): true argmax block kept
  float eps = 1e-3f * sqrtf(ss) + 1e-30f;

  const float* bmrow = blockmax + (size_t)tok * NRB;
  float bv[6];
#pragma unroll
  for (int i = 0; i < 6; ++i) bv[i] = bmrow[lane + 64 * i];   // 384 = 64*6
  float M = fmaxf(fmaxf(fmaxf(bv[0], bv[1]), fmaxf(bv[2], bv[3])), fmaxf(bv[4], bv[5]));
#pragma unroll
  for (int d = 32; d; d >>= 1) M = fmaxf(M, __shfl_xor(M, d));
  float thr = M - eps;

  unsigned long long bk = 0ull;
#pragma unroll
  for (int i = 0; i < 6; ++i) {
    unsigned long long mask = __ballot(bv[i] >= thr);
    while (mask) {                                // wave-uniform loop, expected ~1 iter total
      int l = __ffsll((unsigned long long)mask) - 1;
      mask &= mask - 1;
      int rowb = (l + 64 * i) * RBS;
      for (int r8 = 0; r8 < 8; ++r8) {
        int row = rowb + r8 * 64 + lane;
        if (row < KCB) {
          const float* cv = cb + (size_t)row * DIM;
          float acc = 0.f;
#pragma unroll
          for (int k = 0; k < DIM; ++k) acc = fmaf(av[k], cv[k], acc);  // exact chain
          unsigned long long key = pack_key(acc, row);
          if (key > bk) bk = key;                 // rows ascend per lane -> lowest idx kept
        }
      }
    }
  }
#pragma unroll
  for (int d = 32; d; d >>= 1) {
    unsigned long long o = __shfl_xor(bk, d);
    if (o > bk) bk = o;
  }
  if (lane == 0) best[tok] = bk;
}

// ---------- fused update: gather zq, upsample, z_hat/residual, indices,
// THEN next-scale downsample+pack from the in-LDS updated residual plane ----------
template<int TSZ, int TN>
__global__ __launch_bounds__(256) void update_kernel(const float* __restrict__ cb,
    const unsigned long long* __restrict__ best, float* __restrict__ residual,
    float* __restrict__ out, float* __restrict__ rdown, ushort* __restrict__ th,
    ushort* __restrict__ tl, int idxBase) {
  constexpr int N = TSZ * TSZ;
  constexpr int T = BB * N;
  __shared__ float zq[T * DIM];
  __shared__ float plane[256];
  int tid = threadIdx.x;
  for (int slot = tid; slot < T; slot += 256) {
    unsigned long long key = best[slot];
    int idx = (int)(~(unsigned)key);
    const float* cv = cb + (long long)idx * DIM;
    float v[DIM]; float ss = 0.f;
#pragma unroll
    for (int k = 0; k < DIM; ++k) { v[k] = cv[k]; ss = fmaf(v[k], v[k], ss); }
    float nrm = sqrtf(ss);
#pragma unroll
    for (int k = 0; k < DIM; ++k) zq[slot * DIM + k] = v[k] / nrm;
    if (blockIdx.x == 0) out[idxBase + slot] = (float)idx;
  }
  __syncthreads();
  int e = blockIdx.x * 256 + tid;
  int w = e & 15, h = (e >> 4) & 15;
  int d = (e >> 8) % DIM;
  int b = e / (DIM * 256);
  float inv_scale = (float)TSZ / 16.0f;
  float sf_h = ((float)h + 0.5f) * inv_scale - 0.5f;
  float sf_w = ((float)w + 0.5f) * inv_scale - 0.5f;
  float wh[TSZ], ww[TSZ];
  float sh = 0.f, sw = 0.f;
#pragma unroll
  for (int j = 0; j < TSZ; ++j) {
    float vh = fmaxf(0.f, 1.f - fabsf(sf_h - (float)j));
    wh[j] = vh; sh += vh;
    float vw = fmaxf(0.f, 1.f - fabsf(sf_w - (float)j));
    ww[j] = vw; sw += vw;
  }
#pragma unroll
  for (int j = 0; j < TSZ; ++j) { wh[j] /= sh; ww[j] /= sw; }
  const float* zb = zq + (b * N) * DIM + d;
  float acc = 0.f;
#pragma unroll
  for (int thh = 0; thh < TSZ; ++thh) {
    float ra = 0.f;
#pragma unroll
    for (int tw = 0; tw < TSZ; ++tw) ra = fmaf(ww[tw], zb[(thh * TSZ + tw) * DIM], ra);
    acc = fmaf(wh[thh], ra, acc);
  }
  out[e] += acc;
  float rn = residual[e] - acc;
  residual[e] = rn;

  if constexpr (TN > 0) {                        // next-scale downsample + pack, in-LDS
    plane[tid] = rn;
    __syncthreads();
    constexpr int n2 = TN * TN;
    int bb = blockIdx.x / DIM, dd = blockIdx.x - (blockIdx.x / DIM) * DIM;
    for (int sp = tid; sp < n2; sp += 256) {
      int oh = sp / TN, ow = sp - oh * TN;
      float inv2 = 16.0f / (float)TN;
      float ks = inv2;
      float s_h = ((float)oh + 0.5f) * inv2 - 0.5f;
      float s_w = ((float)ow + 0.5f) * inv2 - 0.5f;
      float wh2[16], ww2[16];
      float sh2 = 0.f, sw2 = 0.f;
#pragma unroll
      for (int i = 0; i < 16; ++i) {
        float vh = fmaxf(0.f, 1.f - fabsf(s_h - (float)i) / ks);
        wh2[i] = vh; sh2 += vh;
        float vw = fmaxf(0.f, 1.f - fabsf(s_w - (float)i) / ks);
        ww2[i] = vw; sw2 += vw;
      }
#pragma unroll
      for (int i = 0; i < 16; ++i) { wh2[i] /= sh2; ww2[i] /= sw2; }
      float acc2 = 0.f;
      for (int ih = 0; ih < 16; ++ih) {
        float ra = 0.f;
#pragma unroll
        for (int iw = 0; iw < 16; ++iw) ra = fmaf(ww2[iw], plane[ih * 16 + iw], ra);
        acc2 = fmaf(wh2[ih], ra, acc2);
      }
      int token = bb * n2 + sp;
      rdown[token * DIM + dd] = acc2;
      unsigned bits = __float_as_uint(acc2);
      float hif = __uint_as_float(bits & 0xffff0000u);
      th[token * DIM + dd] = (ushort)(bits >> 16);
      tl[token * DIM + dd] = (ushort)(__float_as_uint(acc2 - hif) >> 16);
    }
  }
}

// ---------- host ----------
extern "C" void kernel_launch(void* const* d_in, const int* in_sizes, int n_in,
                              void* d_out, int out_size, void* d_ws, size_t ws_size,
                              hipStream_t stream) {
  const float* z  = (const float*)d_in[0];
  const float* cb = (const float*)d_in[1];
  float* out = (float*)d_out;
  float* residual = (float*)d_ws;                          // 12288 f
  float* rdown = residual + ZEL;                           // 12288 f
  float* blockmax = rdown + ZEL;                           // 512*384 f
  unsigned long long* best =
      (unsigned long long*)(blockmax + 512 * NRB);         // 512 u64
  ushort* th = (ushort*)(best + 512);                      // 512*24 u16 token hi
  ushort* tl = th + 512 * 24;                              // 512*24 u16 token lo
  ushort* ch = tl + 512 * 24;                              // 196560*24 u16 codebook hi
  ushort* cl = ch + (size_t)KCB * 24;                      // 196560*24 u16 codebook lo

  static const int TS[10] = {1, 2, 3, 4, 5, 6, 8, 10, 13, 16};

  int initG = (out_size + 255) / 256;
  if (initG < 48) initG = 48;
  init_kernel<<<initG, 256, 0, stream>>>(z, residual, out, rdown, th, tl, out_size);
  cbprep_kernel<<<(KCB * 6 + 255) / 256, 256, 0, stream>>>(cb, ch, cl);

  int prefix = 0;
  for (int s = 0; s < 10; ++s) {
    int t = TS[s], n = t * t, T = BB * n;

    int ntb = (T + 127) >> 7;
    score_kernel<<<NRB * ntb, 256, 0, stream>>>(ch, cl, th, tl, blockmax, T);
    finalize_kernel<<<(T + 3) / 4, 256, 0, stream>>>(cb, rdown, blockmax, best, T);

    int idxBase = ZEL + BB * prefix;
    switch (t) {
      case 1:  update_kernel<1,2><<<48, 256, 0, stream>>>(cb, best, residual, out, rdown, th, tl, idxBase); break;
      case 2:  update_kernel<2,3><<<48, 256, 0, stream>>>(cb, best, residual, out, rdown, th, tl, idxBase); break;
      case 3:  update_kernel<3,4><<<48, 256, 0, stream>>>(cb, best, residual, out, rdown, th, tl, idxBase); break;
      case 4:  update_kernel<4,5><<<48, 256, 0, stream>>>(cb, best, residual, out, rdown, th, tl, idxBase); break;
      case 5:  update_kernel<5,6><<<48, 256, 0, stream>>>(cb, best, residual, out, rdown, th, tl, idxBase); break;
      case 6:  update_kernel<6,8><<<48, 256, 0, stream>>>(cb, best, residual, out, rdown, th, tl, idxBase); break;
      case 8:  update_kernel<8,10><<<48, 256, 0, stream>>>(cb, best, residual, out, rdown, th, tl, idxBase); break;
      case 10: update_kernel<10,13><<<48, 256, 0, stream>>>(cb, best, residual, out, rdown, th, tl, idxBase); break;
      case 13: update_kernel<13,16><<<48, 256, 0, stream>>>(cb, best, residual, out, rdown, th, tl, idxBase); break;
      case 16: update_kernel<16,0><<<48, 256, 0, stream>>>(cb, best, residual, out, rdown, th, tl, idxBase); break;
    }
    prefix += n;
  }
}